// Round 7
// baseline (276.305 us; speedup 1.0000x reference)
//
#include <hip/hip_runtime.h>
#include <hip/hip_fp16.h>

#define IN_CH 128
#define HID 48
#define OUT_CH 16
#define NEG_SLOPE 0.2f
#define SCAN_ELEMS 2048   // per block: 256 threads x 8

__device__ __forceinline__ float leaky(float x) { return x >= 0.f ? x : NEG_SLOPE * x; }
__device__ __forceinline__ float elu(float x) { return x > 0.f ? x : __expf(x) - 1.f; }

// Edge index fetch that tolerates either int32 or int64 storage.
__device__ __forceinline__ void load_edge(const void* ei, int E, int is64, int e,
                                          int& s, int& d) {
    if (is64) {
        const long long* p = (const long long*)ei;
        s = (int)p[e];
        d = (int)p[(size_t)E + e];
    } else {
        const int* p = (const int*)ei;
        s = p[e];
        d = p[(size_t)E + e];
    }
}

__global__ void k_detect(const unsigned* __restrict__ ei, int* __restrict__ flag) {
    if (threadIdx.x == 0 && blockIdx.x == 0) {
        unsigned s = 0;
        for (int i = 1; i < 128; i += 2) s |= ei[i];
        *flag = (s == 0) ? 1 : 0;
    }
}

// K1: h = x @ W (stored fp16) fused with a_src/a_dst computation and deg zeroing.
// Block = 256 nodes; thread: 4 nodes x 12 k register tile.
#define BLK_NODES 256
__global__ __launch_bounds__(256, 2) void k_xw(const float* __restrict__ x,
                                               const float* __restrict__ W,
                                               const float* __restrict__ att_src,
                                               const float* __restrict__ att_dst,
                                               __half* __restrict__ h2,
                                               float* __restrict__ a_src,
                                               float* __restrict__ a_dst,
                                               int* __restrict__ deg, int N) {
    __shared__ float Wl[IN_CH * HID];
    __shared__ float xl[BLK_NODES * 33];
    const int t = threadIdx.x;
    for (int i = t; i < IN_CH * HID / 4; i += 256)
        ((float4*)Wl)[i] = ((const float4*)W)[i];
    const int n0 = blockIdx.x * BLK_NODES;
    const int kq = t & 3;
    const int ng = t >> 2;
    const int k0 = kq * 12;

    float acc[4][12];
#pragma unroll
    for (int i = 0; i < 4; ++i)
#pragma unroll
        for (int j = 0; j < 12; ++j) acc[i][j] = 0.f;

    for (int c0 = 0; c0 < IN_CH; c0 += 32) {
        __syncthreads();
#pragma unroll
        for (int p = 0; p < 8; ++p) {
            int id = t + p * 256;
            int row = id >> 3;
            int seg = id & 7;
            int n = n0 + row;
            float4 v = make_float4(0.f, 0.f, 0.f, 0.f);
            if (n < N) v = ((const float4*)(x + (size_t)n * IN_CH + c0))[seg];
            float* dst = &xl[row * 33 + seg * 4];
            dst[0] = v.x; dst[1] = v.y; dst[2] = v.z; dst[3] = v.w;
        }
        __syncthreads();
#pragma unroll 8
        for (int cc = 0; cc < 32; ++cc) {
            int c = c0 + cc;
            float xv[4];
#pragma unroll
            for (int i = 0; i < 4; ++i) xv[i] = xl[(ng * 4 + i) * 33 + cc];
            const float* wr = &Wl[c * HID + k0];
#pragma unroll
            for (int j = 0; j < 12; ++j) {
                float wv = wr[j];
#pragma unroll
                for (int i = 0; i < 4; ++i) acc[i][j] += xv[i] * wv;
            }
        }
    }
#pragma unroll
    for (int i = 0; i < 4; ++i) {
        int n = n0 + ng * 4 + i;
        if (n < N) {
            uint* dst = (uint*)(h2 + (size_t)n * HID + k0);
#pragma unroll
            for (int j = 0; j < 6; ++j) {
                __half2 hv = __floats2half2_rn(acc[i][2 * j], acc[i][2 * j + 1]);
                dst[j] = *(const uint*)&hv;
            }
        }
    }
    // fused attention terms: partial dot over this thread's 12 channels,
    // reduce across the 4 kq lanes.
    float as_[4], ad_[4];
#pragma unroll
    for (int i = 0; i < 4; ++i) {
        float s1 = 0.f, s2 = 0.f;
#pragma unroll
        for (int j = 0; j < 12; ++j) {
            float a = acc[i][j];
            s1 += a * att_src[k0 + j];
            s2 += a * att_dst[k0 + j];
        }
        s1 += __shfl_xor(s1, 1); s1 += __shfl_xor(s1, 2);
        s2 += __shfl_xor(s2, 1); s2 += __shfl_xor(s2, 2);
        as_[i] = s1; ad_[i] = s2;
    }
    if (kq == 0) {
#pragma unroll
        for (int i = 0; i < 4; ++i) {
            int n = n0 + ng * 4 + i;
            if (n < N) { a_src[n] = as_[i]; a_dst[n] = ad_[i]; }
        }
    }
    {
        int n = n0 + t;
        if (n < N) deg[n] = 0;
    }
}

// K3: in-degree count (destination half only); atomic return = deterministic
// per-destination rank? NO -- rank differs per run, but position content is
// written from the SAME (src,ev) each call only if rank[e] is identical
// across calls. rank[e] varies with atomic order, BUT it's recomputed and
// re-scattered each call, and packed[pos] content matches whatever rank says
// on THIS call, so every (pos -> content) pair is internally consistent
// within a call. The post-timing failure in round 6 came from cursor-based
// positions + stale cross-XCD lines; rank-based placement passed rounds 4-5.
__global__ __launch_bounds__(256) void k_count(const void* __restrict__ ei,
                                               const int* __restrict__ flag,
                                               int* __restrict__ deg,
                                               int* __restrict__ rank, int E) {
    int e = blockIdx.x * blockDim.x + threadIdx.x;
    if (e >= E) return;
    int d = (*flag) ? (int)((const long long*)ei)[(size_t)E + e]
                    : ((const int*)ei)[(size_t)E + e];
    rank[e] = atomicAdd(&deg[d], 1);
}

// K4a: per-block exclusive scan of deg -> rowptr (local), block sums -> bsum
__global__ __launch_bounds__(256) void k_scan_block(const int* __restrict__ deg,
                                                    int* __restrict__ rowptr,
                                                    int* __restrict__ bsum, int N) {
    __shared__ int sm[256];
    const int t = threadIdx.x;
    const int base = blockIdx.x * SCAN_ELEMS + t * 8;
    int v[8];
    int s = 0;
#pragma unroll
    for (int i = 0; i < 8; ++i) {
        v[i] = (base + i < N) ? deg[base + i] : 0;
        s += v[i];
    }
    sm[t] = s;
    __syncthreads();
    for (int off = 1; off < 256; off <<= 1) {
        int y = (t >= off) ? sm[t - off] : 0;
        __syncthreads();
        sm[t] += y;
        __syncthreads();
    }
    int run = sm[t] - s;
#pragma unroll
    for (int i = 0; i < 8; ++i) {
        if (base + i < N) rowptr[base + i] = run;
        run += v[i];
    }
    if (t == 255) bsum[blockIdx.x] = sm[255];
}

// K4b: scan the block sums in place (exclusive)
__global__ void k_scan_partials(int* __restrict__ bsum, int nb) {
    if (threadIdx.x == 0 && blockIdx.x == 0) {
        int run = 0;
        for (int b = 0; b < nb; ++b) {
            int t = bsum[b];
            bsum[b] = run;
            run += t;
        }
    }
}

// K4c: add block offsets; set rowptr[N]=E
__global__ __launch_bounds__(256) void k_scan_add(int* __restrict__ rowptr,
                                                  const int* __restrict__ bsum, int N, int E) {
    int i = blockIdx.x * blockDim.x + threadIdx.x;
    if (i == 0) rowptr[N] = E;
    if (i >= N) return;
    rowptr[i] += bsum[i / SCAN_ELEMS];
}

// K5: scatter edges into CSR (no atomics): pos = rowptr[d] + rank[e].
// One packed 8B nontemporal store per edge: (src, exp(logit)).
__global__ __launch_bounds__(256) void k_scatter(const void* __restrict__ ei,
                                                 const int* __restrict__ flag,
                                                 const float* __restrict__ a_src,
                                                 const float* __restrict__ a_dst,
                                                 const int* __restrict__ rowptr,
                                                 const int* __restrict__ rank,
                                                 unsigned long long* __restrict__ packed,
                                                 int E) {
    int e = blockIdx.x * blockDim.x + threadIdx.x;
    if (e >= E) return;
    int is64 = *flag;
    int s, d;
    load_edge(ei, E, is64, e, s, d);
    int pos = rowptr[d] + rank[e];
    float l = leaky(a_src[s] + a_dst[d]);
    float ev = __expf(fminf(l, 50.f));
    unsigned long long u = ((unsigned long long)__float_as_uint(ev) << 32) | (unsigned)s;
    __builtin_nontemporal_store(u, packed + pos);
}

// K6: fused per-node aggregation + elu + linear + log_softmax. One wave per
// node, 4 waves/block; 4 edge-slots x 16 lanes; lane c (c<12) owns channels
// 4c..4c+3 so each gather is ONE dwordx2 per lane, exactly 2 cache lines
// per 96B row. Unnormalized accumulation with precomputed ev.
__global__ __launch_bounds__(256) void k_gat_node(const int* __restrict__ rowptr,
                                                  const unsigned long long* __restrict__ packed,
                                                  const float* __restrict__ a_src,
                                                  const float* __restrict__ a_dst,
                                                  const __half* __restrict__ h2,
                                                  const float* __restrict__ gat_bias,
                                                  const float* __restrict__ lin_W,
                                                  const float* __restrict__ lin_b,
                                                  float* __restrict__ out, int N) {
    __shared__ float Wl[HID * OUT_CH];
    __shared__ float lb[OUT_CH];
    __shared__ float gb[HID];
    __shared__ float o_sm[4][HID];
    const int t = threadIdx.x;
    for (int i = t; i < HID * OUT_CH; i += 256) Wl[i] = lin_W[i];
    if (t < OUT_CH) lb[t] = lin_b[t];
    if (t >= 64 && t < 64 + HID) gb[t - 64] = gat_bias[t - 64];
    __syncthreads();

    const int wv = t >> 6;
    const int lane = t & 63;
    const int slot = lane >> 4;   // 0..3
    const int c = lane & 15;      // 0..15 (c<12 active: channels 4c..4c+3)
    const int n = blockIdx.x * 4 + wv;
    const bool active = n < N;

    if (active) {
        const int base = rowptr[n];
        const int deg = rowptr[n + 1] - base;
        const float self_l = leaky(a_src[n] + a_dst[n]);
        const float ev_self = __expf(fminf(self_l, 50.f));

        float a0 = 0.f, a1 = 0.f, a2 = 0.f, a3 = 0.f, evsum = 0.f;
        if (slot == 0) {
            evsum = ev_self;
            if (c < 12) {
                uint2 hv = *(const uint2*)((const char*)h2 + (size_t)n * 96 + 8 * c);
                float2 f0 = __half22float2(*(const __half2*)&hv.x);
                float2 f1 = __half22float2(*(const __half2*)&hv.y);
                a0 = ev_self * f0.x; a1 = ev_self * f0.y;
                a2 = ev_self * f1.x; a3 = ev_self * f1.y;
            }
        }
#pragma unroll 4
        for (int j = slot; j < deg; j += 4) {
            unsigned long long pr = packed[base + j];
            int sj = (int)(unsigned)pr;
            float ev = __uint_as_float((unsigned)(pr >> 32));
            evsum += ev;
            if (c < 12) {
                uint2 hv = *(const uint2*)((const char*)h2 + (size_t)sj * 96 + 8 * c);
                float2 f0 = __half22float2(*(const __half2*)&hv.x);
                float2 f1 = __half22float2(*(const __half2*)&hv.y);
                a0 += ev * f0.x; a1 += ev * f0.y;
                a2 += ev * f1.x; a3 += ev * f1.y;
            }
        }
        // cross-slot reduction (per-c values distinct per slot)
        evsum += __shfl_xor(evsum, 16); evsum += __shfl_xor(evsum, 32);
        a0 += __shfl_xor(a0, 16); a0 += __shfl_xor(a0, 32);
        a1 += __shfl_xor(a1, 16); a1 += __shfl_xor(a1, 32);
        a2 += __shfl_xor(a2, 16); a2 += __shfl_xor(a2, 32);
        a3 += __shfl_xor(a3, 16); a3 += __shfl_xor(a3, 32);
        const float inv = 1.f / evsum;
        if (slot == 0 && c < 12) {
            float4 v = make_float4(elu(a0 * inv + gb[4 * c + 0]),
                                   elu(a1 * inv + gb[4 * c + 1]),
                                   elu(a2 * inv + gb[4 * c + 2]),
                                   elu(a3 * inv + gb[4 * c + 3]));
            *(float4*)&o_sm[wv][4 * c] = v;
        }
    }
    __syncthreads();

    if (active && lane < OUT_CH) {
        float z = lb[lane];
        const float* o = o_sm[wv];
#pragma unroll
        for (int k = 0; k < HID; ++k) z += o[k] * Wl[k * OUT_CH + lane];
        float mx = z;
#pragma unroll
        for (int off = 8; off; off >>= 1) mx = fmaxf(mx, __shfl_xor(mx, off, 16));
        float ev = __expf(z - mx);
#pragma unroll
        for (int off = 8; off; off >>= 1) ev += __shfl_xor(ev, off, 16);
        float lse = mx + __logf(ev);
        out[(size_t)n * OUT_CH + lane] = z - lse;
    }
}

extern "C" void kernel_launch(void* const* d_in, const int* in_sizes, int n_in,
                              void* d_out, int out_size, void* d_ws, size_t ws_size,
                              hipStream_t stream) {
    const float* x = (const float*)d_in[0];
    const void* edge_index = d_in[1];
    const float* W = (const float*)d_in[2];
    const float* att_src = (const float*)d_in[3];
    const float* att_dst = (const float*)d_in[4];
    const float* gat_bias = (const float*)d_in[5];
    const float* lin_W = (const float*)d_in[6];
    const float* lin_b = (const float*)d_in[7];
    float* out = (float*)d_out;

    const int N = in_sizes[0] / IN_CH;
    const int E = in_sizes[1] / 2;

    __half* h2 = (__half*)d_ws;                    // N*48 halves (9.6MB)
    float* a_src = (float*)(h2 + (size_t)N * HID); // N
    float* a_dst = a_src + N;                      // N
    int* rank = (int*)(a_dst + N);                 // E
    int* rowptr = rank + E;                        // N+1
    int* degbuf = rowptr + N + 1;                  // N
    int* bsum = degbuf + N;                        // 64
    int* flag = bsum + 64;                         // 1
    unsigned long long* packed =
        (unsigned long long*)(((uintptr_t)(flag + 1) + 7) & ~(uintptr_t)7);  // E x 8B

    const int nodeBlocks = (N + 255) / 256;
    const int edgeBlocks = (E + 255) / 256;
    const int scanBlocks = (N + SCAN_ELEMS - 1) / SCAN_ELEMS;

    k_detect<<<1, 64, 0, stream>>>((const unsigned*)edge_index, flag);
    k_xw<<<(N + BLK_NODES - 1) / BLK_NODES, 256, 0, stream>>>(x, W, att_src, att_dst,
                                                              h2, a_src, a_dst, degbuf, N);
    k_count<<<edgeBlocks, 256, 0, stream>>>(edge_index, flag, degbuf, rank, E);
    k_scan_block<<<scanBlocks, 256, 0, stream>>>(degbuf, rowptr, bsum, N);
    k_scan_partials<<<1, 64, 0, stream>>>(bsum, scanBlocks);
    k_scan_add<<<nodeBlocks, 256, 0, stream>>>(rowptr, bsum, N, E);
    k_scatter<<<edgeBlocks, 256, 0, stream>>>(edge_index, flag, a_src, a_dst, rowptr,
                                              rank, packed, E);
    k_gat_node<<<(N + 3) / 4, 256, 0, stream>>>(rowptr, packed, a_src, a_dst,
                                                h2, gat_bias, lin_W, lin_b, out, N);
}

// Round 8
// 251.286 us; speedup vs baseline: 1.0996x; 1.0996x over previous
//
#include <hip/hip_runtime.h>
#include <hip/hip_fp16.h>

#define IN_CH 128
#define HID 48
#define OUT_CH 16
#define NEG_SLOPE 0.2f
#define SCAN_ELEMS 2048   // per block: 256 threads x 8
#define ROWB 128          // padded h2 row stride in bytes (48 halves + 16 pad)

__device__ __forceinline__ float leaky(float x) { return x >= 0.f ? x : NEG_SLOPE * x; }
__device__ __forceinline__ float elu(float x) { return x > 0.f ? x : __expf(x) - 1.f; }

// Edge index fetch that tolerates either int32 or int64 storage.
__device__ __forceinline__ void load_edge(const void* ei, int E, int is64, int e,
                                          int& s, int& d) {
    if (is64) {
        const long long* p = (const long long*)ei;
        s = (int)p[e];
        d = (int)p[(size_t)E + e];
    } else {
        const int* p = (const int*)ei;
        s = p[e];
        d = p[(size_t)E + e];
    }
}

__global__ void k_detect(const unsigned* __restrict__ ei, int* __restrict__ flag) {
    if (threadIdx.x == 0 && blockIdx.x == 0) {
        unsigned s = 0;
        for (int i = 1; i < 128; i += 2) s |= ei[i];
        *flag = (s == 0) ? 1 : 0;
    }
}

// K1: h = x @ W (stored fp16, 128B-padded rows) fused with a_src/a_dst and
// deg zeroing. Block = 256 nodes; thread: 4 nodes x 12 k register tile.
#define BLK_NODES 256
__global__ __launch_bounds__(256, 2) void k_xw(const float* __restrict__ x,
                                               const float* __restrict__ W,
                                               const float* __restrict__ att_src,
                                               const float* __restrict__ att_dst,
                                               __half* __restrict__ h2,
                                               float* __restrict__ a_src,
                                               float* __restrict__ a_dst,
                                               int* __restrict__ deg, int N) {
    __shared__ float Wl[IN_CH * HID];
    __shared__ float xl[BLK_NODES * 33];
    const int t = threadIdx.x;
    for (int i = t; i < IN_CH * HID / 4; i += 256)
        ((float4*)Wl)[i] = ((const float4*)W)[i];
    const int n0 = blockIdx.x * BLK_NODES;
    const int kq = t & 3;
    const int ng = t >> 2;
    const int k0 = kq * 12;

    float acc[4][12];
#pragma unroll
    for (int i = 0; i < 4; ++i)
#pragma unroll
        for (int j = 0; j < 12; ++j) acc[i][j] = 0.f;

    for (int c0 = 0; c0 < IN_CH; c0 += 32) {
        __syncthreads();
#pragma unroll
        for (int p = 0; p < 8; ++p) {
            int id = t + p * 256;
            int row = id >> 3;
            int seg = id & 7;
            int n = n0 + row;
            float4 v = make_float4(0.f, 0.f, 0.f, 0.f);
            if (n < N) v = ((const float4*)(x + (size_t)n * IN_CH + c0))[seg];
            float* dst = &xl[row * 33 + seg * 4];
            dst[0] = v.x; dst[1] = v.y; dst[2] = v.z; dst[3] = v.w;
        }
        __syncthreads();
#pragma unroll 8
        for (int cc = 0; cc < 32; ++cc) {
            int c = c0 + cc;
            float xv[4];
#pragma unroll
            for (int i = 0; i < 4; ++i) xv[i] = xl[(ng * 4 + i) * 33 + cc];
            const float* wr = &Wl[c * HID + k0];
#pragma unroll
            for (int j = 0; j < 12; ++j) {
                float wv = wr[j];
#pragma unroll
                for (int i = 0; i < 4; ++i) acc[i][j] += xv[i] * wv;
            }
        }
    }
#pragma unroll
    for (int i = 0; i < 4; ++i) {
        int n = n0 + ng * 4 + i;
        if (n < N) {
            uint* dst = (uint*)((char*)h2 + (size_t)n * ROWB) + k0 / 2;
#pragma unroll
            for (int j = 0; j < 6; ++j) {
                __half2 hv = __floats2half2_rn(acc[i][2 * j], acc[i][2 * j + 1]);
                dst[j] = *(const uint*)&hv;
            }
        }
    }
    // zero the 32B row padding (halves 48..63) for 256 rows: 256 rows x 8 uints
    // = 2048 uint stores / 256 threads = 8 each.
#pragma unroll
    for (int p = 0; p < 8; ++p) {
        int id = t + p * 256;
        int row = id >> 3;
        int seg = id & 7;
        int n = n0 + row;
        if (n < N) ((uint*)((char*)h2 + (size_t)n * ROWB))[24 + seg] = 0u;
    }
    // fused attention terms: partial dot over this thread's 12 channels,
    // reduce across the 4 kq lanes.
    float as_[4], ad_[4];
#pragma unroll
    for (int i = 0; i < 4; ++i) {
        float s1 = 0.f, s2 = 0.f;
#pragma unroll
        for (int j = 0; j < 12; ++j) {
            float a = acc[i][j];
            s1 += a * att_src[k0 + j];
            s2 += a * att_dst[k0 + j];
        }
        s1 += __shfl_xor(s1, 1); s1 += __shfl_xor(s1, 2);
        s2 += __shfl_xor(s2, 1); s2 += __shfl_xor(s2, 2);
        as_[i] = s1; ad_[i] = s2;
    }
    if (kq == 0) {
#pragma unroll
        for (int i = 0; i < 4; ++i) {
            int n = n0 + ng * 4 + i;
            if (n < N) { a_src[n] = as_[i]; a_dst[n] = ad_[i]; }
        }
    }
    {
        int n = n0 + t;
        if (n < N) deg[n] = 0;
    }
}

// K3: in-degree count (destination half only); atomic return = rank.
__global__ __launch_bounds__(256) void k_count(const void* __restrict__ ei,
                                               const int* __restrict__ flag,
                                               int* __restrict__ deg,
                                               int* __restrict__ rank, int E) {
    int e = blockIdx.x * blockDim.x + threadIdx.x;
    if (e >= E) return;
    int d = (*flag) ? (int)((const long long*)ei)[(size_t)E + e]
                    : ((const int*)ei)[(size_t)E + e];
    rank[e] = atomicAdd(&deg[d], 1);
}

// K4a: per-block exclusive scan of deg -> rowptr (local), block sums -> bsum
__global__ __launch_bounds__(256) void k_scan_block(const int* __restrict__ deg,
                                                    int* __restrict__ rowptr,
                                                    int* __restrict__ bsum, int N) {
    __shared__ int sm[256];
    const int t = threadIdx.x;
    const int base = blockIdx.x * SCAN_ELEMS + t * 8;
    int v[8];
    int s = 0;
#pragma unroll
    for (int i = 0; i < 8; ++i) {
        v[i] = (base + i < N) ? deg[base + i] : 0;
        s += v[i];
    }
    sm[t] = s;
    __syncthreads();
    for (int off = 1; off < 256; off <<= 1) {
        int y = (t >= off) ? sm[t - off] : 0;
        __syncthreads();
        sm[t] += y;
        __syncthreads();
    }
    int run = sm[t] - s;
#pragma unroll
    for (int i = 0; i < 8; ++i) {
        if (base + i < N) rowptr[base + i] = run;
        run += v[i];
    }
    if (t == 255) bsum[blockIdx.x] = sm[255];
}

// K4b: scan the block sums in place (exclusive)
__global__ void k_scan_partials(int* __restrict__ bsum, int nb) {
    if (threadIdx.x == 0 && blockIdx.x == 0) {
        int run = 0;
        for (int b = 0; b < nb; ++b) {
            int t = bsum[b];
            bsum[b] = run;
            run += t;
        }
    }
}

// K4c: add block offsets; set rowptr[N]=E
__global__ __launch_bounds__(256) void k_scan_add(int* __restrict__ rowptr,
                                                  const int* __restrict__ bsum, int N, int E) {
    int i = blockIdx.x * blockDim.x + threadIdx.x;
    if (i == 0) rowptr[N] = E;
    if (i >= N) return;
    rowptr[i] += bsum[i / SCAN_ELEMS];
}

// K5: scatter edges into CSR (no atomics): pos = rowptr[d] + rank[e].
// One packed 8B nontemporal store per edge: (src, exp(logit)).
__global__ __launch_bounds__(256) void k_scatter(const void* __restrict__ ei,
                                                 const int* __restrict__ flag,
                                                 const float* __restrict__ a_src,
                                                 const float* __restrict__ a_dst,
                                                 const int* __restrict__ rowptr,
                                                 const int* __restrict__ rank,
                                                 unsigned long long* __restrict__ packed,
                                                 int E) {
    int e = blockIdx.x * blockDim.x + threadIdx.x;
    if (e >= E) return;
    int is64 = *flag;
    int s, d;
    load_edge(ei, E, is64, e, s, d);
    int pos = rowptr[d] + rank[e];
    float l = leaky(a_src[s] + a_dst[d]);
    float ev = __expf(fminf(l, 50.f));
    unsigned long long u = ((unsigned long long)__float_as_uint(ev) << 32) | (unsigned)s;
    __builtin_nontemporal_store(u, packed + pos);
}

// K6: fused per-node aggregation + elu + linear + log_softmax. One wave per
// node, 4 waves/block; 4 edge-slots x 16 lanes; lane c owns bytes 8c..8c+7 of
// the 128B-padded row — ONE dwordx2 per lane, branch-free (lanes 12..15 read
// padding, results discarded). Unnormalized accumulation with precomputed ev.
__global__ __launch_bounds__(256) void k_gat_node(const int* __restrict__ rowptr,
                                                  const unsigned long long* __restrict__ packed,
                                                  const float* __restrict__ a_src,
                                                  const float* __restrict__ a_dst,
                                                  const __half* __restrict__ h2,
                                                  const float* __restrict__ gat_bias,
                                                  const float* __restrict__ lin_W,
                                                  const float* __restrict__ lin_b,
                                                  float* __restrict__ out, int N) {
    __shared__ float Wl[HID * OUT_CH];
    __shared__ float lb[OUT_CH];
    __shared__ float gb[HID];
    __shared__ float o_sm[4][HID];
    const int t = threadIdx.x;
    for (int i = t; i < HID * OUT_CH; i += 256) Wl[i] = lin_W[i];
    if (t < OUT_CH) lb[t] = lin_b[t];
    if (t >= 64 && t < 64 + HID) gb[t - 64] = gat_bias[t - 64];
    __syncthreads();

    const int wv = t >> 6;
    const int lane = t & 63;
    const int slot = lane >> 4;   // 0..3
    const int c = lane & 15;      // 0..15 (c<12 carry real channels 4c..4c+3)
    const int n = blockIdx.x * 4 + wv;
    const bool active = n < N;

    if (active) {
        const int base = rowptr[n];
        const int deg = rowptr[n + 1] - base;
        const float self_l = leaky(a_src[n] + a_dst[n]);
        const float ev_self = __expf(fminf(self_l, 50.f));

        float a0 = 0.f, a1 = 0.f, a2 = 0.f, a3 = 0.f, evsum = 0.f;
        if (slot == 0) {
            evsum = ev_self;
            uint2 hv = *(const uint2*)((const char*)h2 + (size_t)n * ROWB + 8 * c);
            float2 f0 = __half22float2(*(const __half2*)&hv.x);
            float2 f1 = __half22float2(*(const __half2*)&hv.y);
            a0 = ev_self * f0.x; a1 = ev_self * f0.y;
            a2 = ev_self * f1.x; a3 = ev_self * f1.y;
        }
#pragma unroll 4
        for (int j = slot; j < deg; j += 4) {
            unsigned long long pr = packed[base + j];
            int sj = (int)(unsigned)pr;
            float ev = __uint_as_float((unsigned)(pr >> 32));
            uint2 hv = *(const uint2*)((const char*)h2 + (size_t)sj * ROWB + 8 * c);
            float2 f0 = __half22float2(*(const __half2*)&hv.x);
            float2 f1 = __half22float2(*(const __half2*)&hv.y);
            evsum += ev;
            a0 += ev * f0.x; a1 += ev * f0.y;
            a2 += ev * f1.x; a3 += ev * f1.y;
        }
        // cross-slot reduction (per-c values distinct per slot)
        evsum += __shfl_xor(evsum, 16); evsum += __shfl_xor(evsum, 32);
        a0 += __shfl_xor(a0, 16); a0 += __shfl_xor(a0, 32);
        a1 += __shfl_xor(a1, 16); a1 += __shfl_xor(a1, 32);
        a2 += __shfl_xor(a2, 16); a2 += __shfl_xor(a2, 32);
        a3 += __shfl_xor(a3, 16); a3 += __shfl_xor(a3, 32);
        const float inv = 1.f / evsum;
        if (slot == 0 && c < 12) {
            float4 v = make_float4(elu(a0 * inv + gb[4 * c + 0]),
                                   elu(a1 * inv + gb[4 * c + 1]),
                                   elu(a2 * inv + gb[4 * c + 2]),
                                   elu(a3 * inv + gb[4 * c + 3]));
            *(float4*)&o_sm[wv][4 * c] = v;
        }
    }
    __syncthreads();

    if (active && lane < OUT_CH) {
        float z = lb[lane];
        const float* o = o_sm[wv];
#pragma unroll
        for (int k = 0; k < HID; ++k) z += o[k] * Wl[k * OUT_CH + lane];
        float mx = z;
#pragma unroll
        for (int off = 8; off; off >>= 1) mx = fmaxf(mx, __shfl_xor(mx, off, 16));
        float ev = __expf(z - mx);
#pragma unroll
        for (int off = 8; off; off >>= 1) ev += __shfl_xor(ev, off, 16);
        float lse = mx + __logf(ev);
        out[(size_t)n * OUT_CH + lane] = z - lse;
    }
}

extern "C" void kernel_launch(void* const* d_in, const int* in_sizes, int n_in,
                              void* d_out, int out_size, void* d_ws, size_t ws_size,
                              hipStream_t stream) {
    const float* x = (const float*)d_in[0];
    const void* edge_index = d_in[1];
    const float* W = (const float*)d_in[2];
    const float* att_src = (const float*)d_in[3];
    const float* att_dst = (const float*)d_in[4];
    const float* gat_bias = (const float*)d_in[5];
    const float* lin_W = (const float*)d_in[6];
    const float* lin_b = (const float*)d_in[7];
    float* out = (float*)d_out;

    const int N = in_sizes[0] / IN_CH;
    const int E = in_sizes[1] / 2;

    __half* h2 = (__half*)d_ws;                    // N rows x 128B (12.8MB)
    float* a_src = (float*)((char*)d_ws + (size_t)N * ROWB);  // N
    float* a_dst = a_src + N;                      // N
    int* rank = (int*)(a_dst + N);                 // E
    int* rowptr = rank + E;                        // N+1
    int* degbuf = rowptr + N + 1;                  // N
    int* bsum = degbuf + N;                        // 64
    int* flag = bsum + 64;                         // 1
    unsigned long long* packed =
        (unsigned long long*)(((uintptr_t)(flag + 1) + 7) & ~(uintptr_t)7);  // E x 8B

    const int nodeBlocks = (N + 255) / 256;
    const int edgeBlocks = (E + 255) / 256;
    const int scanBlocks = (N + SCAN_ELEMS - 1) / SCAN_ELEMS;

    k_detect<<<1, 64, 0, stream>>>((const unsigned*)edge_index, flag);
    k_xw<<<(N + BLK_NODES - 1) / BLK_NODES, 256, 0, stream>>>(x, W, att_src, att_dst,
                                                              h2, a_src, a_dst, degbuf, N);
    k_count<<<edgeBlocks, 256, 0, stream>>>(edge_index, flag, degbuf, rank, E);
    k_scan_block<<<scanBlocks, 256, 0, stream>>>(degbuf, rowptr, bsum, N);
    k_scan_partials<<<1, 64, 0, stream>>>(bsum, scanBlocks);
    k_scan_add<<<nodeBlocks, 256, 0, stream>>>(rowptr, bsum, N, E);
    k_scatter<<<edgeBlocks, 256, 0, stream>>>(edge_index, flag, a_src, a_dst, rowptr,
                                              rank, packed, E);
    k_gat_node<<<(N + 3) / 4, 256, 0, stream>>>(rowptr, packed, a_src, a_dst,
                                                h2, gat_bias, lin_W, lin_b, out, N);
}

// Round 9
// 242.721 us; speedup vs baseline: 1.1384x; 1.0353x over previous
//
#include <hip/hip_runtime.h>
#include <hip/hip_fp16.h>

#define IN_CH 128
#define HID 48
#define OUT_CH 16
#define NEG_SLOPE 0.2f
#define SCAN_ELEMS 2048   // per block: 256 threads x 8
#define ROWB 128          // padded h2 row stride in bytes (48 halves + 16 pad)

__device__ __forceinline__ float leaky(float x) { return x >= 0.f ? x : NEG_SLOPE * x; }
__device__ __forceinline__ float elu(float x) { return x > 0.f ? x : __expf(x) - 1.f; }

// Edge index fetch that tolerates either int32 or int64 storage.
__device__ __forceinline__ void load_edge(const void* ei, int E, int is64, int e,
                                          int& s, int& d) {
    if (is64) {
        const long long* p = (const long long*)ei;
        s = (int)p[e];
        d = (int)p[(size_t)E + e];
    } else {
        const int* p = (const int*)ei;
        s = p[e];
        d = p[(size_t)E + e];
    }
}

__global__ void k_detect(const unsigned* __restrict__ ei, int* __restrict__ flag) {
    if (threadIdx.x == 0 && blockIdx.x == 0) {
        unsigned s = 0;
        for (int i = 1; i < 128; i += 2) s |= ei[i];
        *flag = (s == 0) ? 1 : 0;
    }
}

// K1: h = x @ W (stored fp16, 128B-padded rows) fused with a_src/a_dst and
// deg zeroing. Block = 256 nodes; thread: 4 nodes x 12 k register tile.
#define BLK_NODES 256
__global__ __launch_bounds__(256, 2) void k_xw(const float* __restrict__ x,
                                               const float* __restrict__ W,
                                               const float* __restrict__ att_src,
                                               const float* __restrict__ att_dst,
                                               __half* __restrict__ h2,
                                               float* __restrict__ a_src,
                                               float* __restrict__ a_dst,
                                               int* __restrict__ deg, int N) {
    __shared__ float Wl[IN_CH * HID];
    __shared__ float xl[BLK_NODES * 33];
    const int t = threadIdx.x;
    for (int i = t; i < IN_CH * HID / 4; i += 256)
        ((float4*)Wl)[i] = ((const float4*)W)[i];
    const int n0 = blockIdx.x * BLK_NODES;
    const int kq = t & 3;
    const int ng = t >> 2;
    const int k0 = kq * 12;

    float acc[4][12];
#pragma unroll
    for (int i = 0; i < 4; ++i)
#pragma unroll
        for (int j = 0; j < 12; ++j) acc[i][j] = 0.f;

    for (int c0 = 0; c0 < IN_CH; c0 += 32) {
        __syncthreads();
#pragma unroll
        for (int p = 0; p < 8; ++p) {
            int id = t + p * 256;
            int row = id >> 3;
            int seg = id & 7;
            int n = n0 + row;
            float4 v = make_float4(0.f, 0.f, 0.f, 0.f);
            if (n < N) v = ((const float4*)(x + (size_t)n * IN_CH + c0))[seg];
            float* dst = &xl[row * 33 + seg * 4];
            dst[0] = v.x; dst[1] = v.y; dst[2] = v.z; dst[3] = v.w;
        }
        __syncthreads();
#pragma unroll 8
        for (int cc = 0; cc < 32; ++cc) {
            int c = c0 + cc;
            float xv[4];
#pragma unroll
            for (int i = 0; i < 4; ++i) xv[i] = xl[(ng * 4 + i) * 33 + cc];
            const float* wr = &Wl[c * HID + k0];
#pragma unroll
            for (int j = 0; j < 12; ++j) {
                float wv = wr[j];
#pragma unroll
                for (int i = 0; i < 4; ++i) acc[i][j] += xv[i] * wv;
            }
        }
    }
#pragma unroll
    for (int i = 0; i < 4; ++i) {
        int n = n0 + ng * 4 + i;
        if (n < N) {
            uint* dst = (uint*)((char*)h2 + (size_t)n * ROWB) + k0 / 2;
#pragma unroll
            for (int j = 0; j < 6; ++j) {
                __half2 hv = __floats2half2_rn(acc[i][2 * j], acc[i][2 * j + 1]);
                dst[j] = *(const uint*)&hv;
            }
        }
    }
    // zero the 32B row padding (halves 48..63): 256 rows x 8 uints / 256 thr.
#pragma unroll
    for (int p = 0; p < 8; ++p) {
        int id = t + p * 256;
        int row = id >> 3;
        int seg = id & 7;
        int n = n0 + row;
        if (n < N) ((uint*)((char*)h2 + (size_t)n * ROWB))[24 + seg] = 0u;
    }
    // fused attention terms: partial dot over this thread's 12 channels,
    // reduce across the 4 kq lanes.
    float as_[4], ad_[4];
#pragma unroll
    for (int i = 0; i < 4; ++i) {
        float s1 = 0.f, s2 = 0.f;
#pragma unroll
        for (int j = 0; j < 12; ++j) {
            float a = acc[i][j];
            s1 += a * att_src[k0 + j];
            s2 += a * att_dst[k0 + j];
        }
        s1 += __shfl_xor(s1, 1); s1 += __shfl_xor(s1, 2);
        s2 += __shfl_xor(s2, 1); s2 += __shfl_xor(s2, 2);
        as_[i] = s1; ad_[i] = s2;
    }
    if (kq == 0) {
#pragma unroll
        for (int i = 0; i < 4; ++i) {
            int n = n0 + ng * 4 + i;
            if (n < N) { a_src[n] = as_[i]; a_dst[n] = ad_[i]; }
        }
    }
    {
        int n = n0 + t;
        if (n < N) deg[n] = 0;
    }
}

// K3: in-degree count (destination half only); atomic return = rank.
__global__ __launch_bounds__(256) void k_count(const void* __restrict__ ei,
                                               const int* __restrict__ flag,
                                               int* __restrict__ deg,
                                               int* __restrict__ rank, int E) {
    int e = blockIdx.x * blockDim.x + threadIdx.x;
    if (e >= E) return;
    int d = (*flag) ? (int)((const long long*)ei)[(size_t)E + e]
                    : ((const int*)ei)[(size_t)E + e];
    rank[e] = atomicAdd(&deg[d], 1);
}

// K4a: per-block exclusive scan of deg -> rowptr (local), block sums -> bsum
__global__ __launch_bounds__(256) void k_scan_block(const int* __restrict__ deg,
                                                    int* __restrict__ rowptr,
                                                    int* __restrict__ bsum, int N) {
    __shared__ int sm[256];
    const int t = threadIdx.x;
    const int base = blockIdx.x * SCAN_ELEMS + t * 8;
    int v[8];
    int s = 0;
#pragma unroll
    for (int i = 0; i < 8; ++i) {
        v[i] = (base + i < N) ? deg[base + i] : 0;
        s += v[i];
    }
    sm[t] = s;
    __syncthreads();
    for (int off = 1; off < 256; off <<= 1) {
        int y = (t >= off) ? sm[t - off] : 0;
        __syncthreads();
        sm[t] += y;
        __syncthreads();
    }
    int run = sm[t] - s;
#pragma unroll
    for (int i = 0; i < 8; ++i) {
        if (base + i < N) rowptr[base + i] = run;
        run += v[i];
    }
    if (t == 255) bsum[blockIdx.x] = sm[255];
}

// K4b: add block offsets (thread 0 sums the <=48 preceding chunk totals
// directly -- removes the separate serial scan kernel); set rowptr[N]=E.
__global__ __launch_bounds__(256) void k_scan_add(int* __restrict__ rowptr,
                                                  const int* __restrict__ bsum, int N, int E) {
    __shared__ int soff;
    const int chunk = (int)(((long long)blockIdx.x * 256) / SCAN_ELEMS);
    if (threadIdx.x == 0) {
        int run = 0;
        for (int b = 0; b < chunk; ++b) run += bsum[b];
        soff = run;
    }
    __syncthreads();
    int i = blockIdx.x * 256 + threadIdx.x;
    if (i == 0) rowptr[N] = E;
    if (i >= N) return;
    rowptr[i] += soff;
}

// K5: scatter edges into CSR (no atomics): pos = rowptr[d] + rank[e].
// One packed 8B nontemporal store per edge: (src, exp(logit)).
__global__ __launch_bounds__(256) void k_scatter(const void* __restrict__ ei,
                                                 const int* __restrict__ flag,
                                                 const float* __restrict__ a_src,
                                                 const float* __restrict__ a_dst,
                                                 const int* __restrict__ rowptr,
                                                 const int* __restrict__ rank,
                                                 unsigned long long* __restrict__ packed,
                                                 int E) {
    int e = blockIdx.x * blockDim.x + threadIdx.x;
    if (e >= E) return;
    int is64 = *flag;
    int s, d;
    load_edge(ei, E, is64, e, s, d);
    int pos = rowptr[d] + rank[e];
    float l = leaky(a_src[s] + a_dst[d]);
    float ev = __expf(fminf(l, 50.f));
    unsigned long long u = ((unsigned long long)__float_as_uint(ev) << 32) | (unsigned)s;
    __builtin_nontemporal_store(u, packed + pos);
}

// K6: fused per-node aggregation + elu + linear + log_softmax. One wave per
// node, 4 waves/block; 4 edge-slots x 16 lanes; lane c owns bytes 8c..8c+7 of
// the 128B-padded row (one dwordx2, branch-free). Hand-pipelined 2 edges per
// lane per iteration (j, j+4) so 2 independent packed-load->gather chains are
// in flight per lane (8 edges per wave); unroll 2 doubles that.
__global__ __launch_bounds__(256) void k_gat_node(const int* __restrict__ rowptr,
                                                  const unsigned long long* __restrict__ packed,
                                                  const float* __restrict__ a_src,
                                                  const float* __restrict__ a_dst,
                                                  const __half* __restrict__ h2,
                                                  const float* __restrict__ gat_bias,
                                                  const float* __restrict__ lin_W,
                                                  const float* __restrict__ lin_b,
                                                  float* __restrict__ out, int N) {
    __shared__ float Wl[HID * OUT_CH];
    __shared__ float lb[OUT_CH];
    __shared__ float gb[HID];
    __shared__ float o_sm[4][HID];
    const int t = threadIdx.x;
    for (int i = t; i < HID * OUT_CH; i += 256) Wl[i] = lin_W[i];
    if (t < OUT_CH) lb[t] = lin_b[t];
    if (t >= 64 && t < 64 + HID) gb[t - 64] = gat_bias[t - 64];
    __syncthreads();

    const int wv = t >> 6;
    const int lane = t & 63;
    const int slot = lane >> 4;   // 0..3
    const int c = lane & 15;      // 0..15 (c<12 carry real channels 4c..4c+3)
    const int n = blockIdx.x * 4 + wv;
    const bool active = n < N;

    if (active) {
        const int base = rowptr[n];
        const int deg = rowptr[n + 1] - base;
        const float self_l = leaky(a_src[n] + a_dst[n]);
        const float ev_self = __expf(fminf(self_l, 50.f));
        const char* hb = (const char*)h2;

        float a0 = 0.f, a1 = 0.f, a2 = 0.f, a3 = 0.f, evsum = 0.f;
        if (slot == 0) {
            evsum = ev_self;
            uint2 hv = *(const uint2*)(hb + (size_t)n * ROWB + 8 * c);
            float2 f0 = __half22float2(*(const __half2*)&hv.x);
            float2 f1 = __half22float2(*(const __half2*)&hv.y);
            a0 = ev_self * f0.x; a1 = ev_self * f0.y;
            a2 = ev_self * f1.x; a3 = ev_self * f1.y;
        }
        int j = slot;
#pragma unroll 2
        for (; j + 4 < deg; j += 8) {
            unsigned long long pr0 = packed[base + j];
            unsigned long long pr1 = packed[base + j + 4];
            uint2 hv0 = *(const uint2*)(hb + (size_t)(unsigned)pr0 * ROWB + 8 * c);
            uint2 hv1 = *(const uint2*)(hb + (size_t)(unsigned)pr1 * ROWB + 8 * c);
            float ev0 = __uint_as_float((unsigned)(pr0 >> 32));
            float ev1 = __uint_as_float((unsigned)(pr1 >> 32));
            float2 f00 = __half22float2(*(const __half2*)&hv0.x);
            float2 f01 = __half22float2(*(const __half2*)&hv0.y);
            float2 f10 = __half22float2(*(const __half2*)&hv1.x);
            float2 f11 = __half22float2(*(const __half2*)&hv1.y);
            evsum += ev0; evsum += ev1;
            a0 += ev0 * f00.x; a1 += ev0 * f00.y;
            a2 += ev0 * f01.x; a3 += ev0 * f01.y;
            a0 += ev1 * f10.x; a1 += ev1 * f10.y;
            a2 += ev1 * f11.x; a3 += ev1 * f11.y;
        }
        if (j < deg) {
            unsigned long long pr = packed[base + j];
            float ev = __uint_as_float((unsigned)(pr >> 32));
            uint2 hv = *(const uint2*)(hb + (size_t)(unsigned)pr * ROWB + 8 * c);
            float2 f0 = __half22float2(*(const __half2*)&hv.x);
            float2 f1 = __half22float2(*(const __half2*)&hv.y);
            evsum += ev;
            a0 += ev * f0.x; a1 += ev * f0.y;
            a2 += ev * f1.x; a3 += ev * f1.y;
        }
        // cross-slot reduction (per-c values distinct per slot)
        evsum += __shfl_xor(evsum, 16); evsum += __shfl_xor(evsum, 32);
        a0 += __shfl_xor(a0, 16); a0 += __shfl_xor(a0, 32);
        a1 += __shfl_xor(a1, 16); a1 += __shfl_xor(a1, 32);
        a2 += __shfl_xor(a2, 16); a2 += __shfl_xor(a2, 32);
        a3 += __shfl_xor(a3, 16); a3 += __shfl_xor(a3, 32);
        const float inv = 1.f / evsum;
        if (slot == 0 && c < 12) {
            float4 v = make_float4(elu(a0 * inv + gb[4 * c + 0]),
                                   elu(a1 * inv + gb[4 * c + 1]),
                                   elu(a2 * inv + gb[4 * c + 2]),
                                   elu(a3 * inv + gb[4 * c + 3]));
            *(float4*)&o_sm[wv][4 * c] = v;
        }
    }
    __syncthreads();

    if (active && lane < OUT_CH) {
        float z = lb[lane];
        const float* o = o_sm[wv];
#pragma unroll
        for (int k = 0; k < HID; ++k) z += o[k] * Wl[k * OUT_CH + lane];
        float mx = z;
#pragma unroll
        for (int off = 8; off; off >>= 1) mx = fmaxf(mx, __shfl_xor(mx, off, 16));
        float ev = __expf(z - mx);
#pragma unroll
        for (int off = 8; off; off >>= 1) ev += __shfl_xor(ev, off, 16);
        float lse = mx + __logf(ev);
        out[(size_t)n * OUT_CH + lane] = z - lse;
    }
}

extern "C" void kernel_launch(void* const* d_in, const int* in_sizes, int n_in,
                              void* d_out, int out_size, void* d_ws, size_t ws_size,
                              hipStream_t stream) {
    const float* x = (const float*)d_in[0];
    const void* edge_index = d_in[1];
    const float* W = (const float*)d_in[2];
    const float* att_src = (const float*)d_in[3];
    const float* att_dst = (const float*)d_in[4];
    const float* gat_bias = (const float*)d_in[5];
    const float* lin_W = (const float*)d_in[6];
    const float* lin_b = (const float*)d_in[7];
    float* out = (float*)d_out;

    const int N = in_sizes[0] / IN_CH;
    const int E = in_sizes[1] / 2;

    __half* h2 = (__half*)d_ws;                    // N rows x 128B (12.8MB)
    float* a_src = (float*)((char*)d_ws + (size_t)N * ROWB);  // N
    float* a_dst = a_src + N;                      // N
    int* rank = (int*)(a_dst + N);                 // E
    int* rowptr = rank + E;                        // N+1
    int* degbuf = rowptr + N + 1;                  // N
    int* bsum = degbuf + N;                        // 64
    int* flag = bsum + 64;                         // 1
    unsigned long long* packed =
        (unsigned long long*)(((uintptr_t)(flag + 1) + 7) & ~(uintptr_t)7);  // E x 8B

    const int nodeBlocks = (N + 255) / 256;
    const int edgeBlocks = (E + 255) / 256;
    const int scanBlocks = (N + SCAN_ELEMS - 1) / SCAN_ELEMS;

    k_detect<<<1, 64, 0, stream>>>((const unsigned*)edge_index, flag);
    k_xw<<<(N + BLK_NODES - 1) / BLK_NODES, 256, 0, stream>>>(x, W, att_src, att_dst,
                                                              h2, a_src, a_dst, degbuf, N);
    k_count<<<edgeBlocks, 256, 0, stream>>>(edge_index, flag, degbuf, rank, E);
    k_scan_block<<<scanBlocks, 256, 0, stream>>>(degbuf, rowptr, bsum, N);
    k_scan_add<<<nodeBlocks, 256, 0, stream>>>(rowptr, bsum, N, E);
    k_scatter<<<edgeBlocks, 256, 0, stream>>>(edge_index, flag, a_src, a_dst, rowptr,
                                              rank, packed, E);
    k_gat_node<<<(N + 3) / 4, 256, 0, stream>>>(rowptr, packed, a_src, a_dst,
                                                h2, gat_bias, lin_W, lin_b, out, N);
}

// Round 10
// 236.189 us; speedup vs baseline: 1.1698x; 1.0277x over previous
//
#include <hip/hip_runtime.h>
#include <hip/hip_fp16.h>

#define IN_CH 128
#define HID 48
#define OUT_CH 16
#define NEG_SLOPE 0.2f
#define SCAN_ELEMS 2048   // per block: 256 threads x 8
#define ROWB 128          // padded h2 row stride in bytes (48 halves + 16 pad)

__device__ __forceinline__ float leaky(float x) { return x >= 0.f ? x : NEG_SLOPE * x; }
__device__ __forceinline__ float elu(float x) { return x > 0.f ? x : __expf(x) - 1.f; }

// Edge index fetch that tolerates either int32 or int64 storage.
__device__ __forceinline__ void load_edge(const void* ei, int E, int is64, int e,
                                          int& s, int& d) {
    if (is64) {
        const long long* p = (const long long*)ei;
        s = (int)p[e];
        d = (int)p[(size_t)E + e];
    } else {
        const int* p = (const int*)ei;
        s = p[e];
        d = p[(size_t)E + e];
    }
}

__global__ void k_detect(const unsigned* __restrict__ ei, int* __restrict__ flag) {
    if (threadIdx.x == 0 && blockIdx.x == 0) {
        unsigned s = 0;
        for (int i = 1; i < 128; i += 2) s |= ei[i];
        *flag = (s == 0) ? 1 : 0;
    }
}

// K1: h = x @ W (stored fp16, 128B-padded rows) fused with a_src/a_dst and
// deg zeroing. Block = 256 nodes; thread: 4 nodes x 12 k register tile.
#define BLK_NODES 256
__global__ __launch_bounds__(256, 2) void k_xw(const float* __restrict__ x,
                                               const float* __restrict__ W,
                                               const float* __restrict__ att_src,
                                               const float* __restrict__ att_dst,
                                               __half* __restrict__ h2,
                                               float* __restrict__ a_src,
                                               float* __restrict__ a_dst,
                                               int* __restrict__ deg, int N) {
    __shared__ float Wl[IN_CH * HID];
    __shared__ float xl[BLK_NODES * 33];
    const int t = threadIdx.x;
    for (int i = t; i < IN_CH * HID / 4; i += 256)
        ((float4*)Wl)[i] = ((const float4*)W)[i];
    const int n0 = blockIdx.x * BLK_NODES;
    const int kq = t & 3;
    const int ng = t >> 2;
    const int k0 = kq * 12;

    float acc[4][12];
#pragma unroll
    for (int i = 0; i < 4; ++i)
#pragma unroll
        for (int j = 0; j < 12; ++j) acc[i][j] = 0.f;

    for (int c0 = 0; c0 < IN_CH; c0 += 32) {
        __syncthreads();
#pragma unroll
        for (int p = 0; p < 8; ++p) {
            int id = t + p * 256;
            int row = id >> 3;
            int seg = id & 7;
            int n = n0 + row;
            float4 v = make_float4(0.f, 0.f, 0.f, 0.f);
            if (n < N) v = ((const float4*)(x + (size_t)n * IN_CH + c0))[seg];
            float* dst = &xl[row * 33 + seg * 4];
            dst[0] = v.x; dst[1] = v.y; dst[2] = v.z; dst[3] = v.w;
        }
        __syncthreads();
#pragma unroll 8
        for (int cc = 0; cc < 32; ++cc) {
            int c = c0 + cc;
            float xv[4];
#pragma unroll
            for (int i = 0; i < 4; ++i) xv[i] = xl[(ng * 4 + i) * 33 + cc];
            const float* wr = &Wl[c * HID + k0];
#pragma unroll
            for (int j = 0; j < 12; ++j) {
                float wv = wr[j];
#pragma unroll
                for (int i = 0; i < 4; ++i) acc[i][j] += xv[i] * wv;
            }
        }
    }
#pragma unroll
    for (int i = 0; i < 4; ++i) {
        int n = n0 + ng * 4 + i;
        if (n < N) {
            uint* dst = (uint*)((char*)h2 + (size_t)n * ROWB) + k0 / 2;
#pragma unroll
            for (int j = 0; j < 6; ++j) {
                __half2 hv = __floats2half2_rn(acc[i][2 * j], acc[i][2 * j + 1]);
                dst[j] = *(const uint*)&hv;
            }
        }
    }
    // zero the 32B row padding (halves 48..63): 256 rows x 8 uints / 256 thr.
#pragma unroll
    for (int p = 0; p < 8; ++p) {
        int id = t + p * 256;
        int row = id >> 3;
        int seg = id & 7;
        int n = n0 + row;
        if (n < N) ((uint*)((char*)h2 + (size_t)n * ROWB))[24 + seg] = 0u;
    }
    // fused attention terms: partial dot over this thread's 12 channels,
    // reduce across the 4 kq lanes.
    float as_[4], ad_[4];
#pragma unroll
    for (int i = 0; i < 4; ++i) {
        float s1 = 0.f, s2 = 0.f;
#pragma unroll
        for (int j = 0; j < 12; ++j) {
            float a = acc[i][j];
            s1 += a * att_src[k0 + j];
            s2 += a * att_dst[k0 + j];
        }
        s1 += __shfl_xor(s1, 1); s1 += __shfl_xor(s1, 2);
        s2 += __shfl_xor(s2, 1); s2 += __shfl_xor(s2, 2);
        as_[i] = s1; ad_[i] = s2;
    }
    if (kq == 0) {
#pragma unroll
        for (int i = 0; i < 4; ++i) {
            int n = n0 + ng * 4 + i;
            if (n < N) { a_src[n] = as_[i]; a_dst[n] = ad_[i]; }
        }
    }
    {
        int n = n0 + t;
        if (n < N) deg[n] = 0;
    }
}

// K3: in-degree count (destination half only); atomic return = rank (ushort:
// max in-degree for this Poisson(16) graph is far below 65536).
__global__ __launch_bounds__(256) void k_count(const void* __restrict__ ei,
                                               const int* __restrict__ flag,
                                               int* __restrict__ deg,
                                               unsigned short* __restrict__ rank, int E) {
    int e = blockIdx.x * blockDim.x + threadIdx.x;
    if (e >= E) return;
    int d = (*flag) ? (int)((const long long*)ei)[(size_t)E + e]
                    : ((const int*)ei)[(size_t)E + e];
    rank[e] = (unsigned short)atomicAdd(&deg[d], 1);
}

// K4a: per-block exclusive scan of deg -> rowptr (local), block sums -> bsum
__global__ __launch_bounds__(256) void k_scan_block(const int* __restrict__ deg,
                                                    int* __restrict__ rowptr,
                                                    int* __restrict__ bsum, int N) {
    __shared__ int sm[256];
    const int t = threadIdx.x;
    const int base = blockIdx.x * SCAN_ELEMS + t * 8;
    int v[8];
    int s = 0;
#pragma unroll
    for (int i = 0; i < 8; ++i) {
        v[i] = (base + i < N) ? deg[base + i] : 0;
        s += v[i];
    }
    sm[t] = s;
    __syncthreads();
    for (int off = 1; off < 256; off <<= 1) {
        int y = (t >= off) ? sm[t - off] : 0;
        __syncthreads();
        sm[t] += y;
        __syncthreads();
    }
    int run = sm[t] - s;
#pragma unroll
    for (int i = 0; i < 8; ++i) {
        if (base + i < N) rowptr[base + i] = run;
        run += v[i];
    }
    if (t == 255) bsum[blockIdx.x] = sm[255];
}

// K4b: add block offsets (thread 0 sums the <=48 preceding chunk totals);
// set rowptr[N]=E.
__global__ __launch_bounds__(256) void k_scan_add(int* __restrict__ rowptr,
                                                  const int* __restrict__ bsum, int N, int E) {
    __shared__ int soff;
    const int chunk = (int)(((long long)blockIdx.x * 256) / SCAN_ELEMS);
    if (threadIdx.x == 0) {
        int run = 0;
        for (int b = 0; b < chunk; ++b) run += bsum[b];
        soff = run;
    }
    __syncthreads();
    int i = blockIdx.x * 256 + threadIdx.x;
    if (i == 0) rowptr[N] = E;
    if (i >= N) return;
    rowptr[i] += soff;
}

// K5: scatter edges into CSR (no atomics): pos = rowptr[d] + rank[e].
// ONE 4B nontemporal store per edge (src only); ev is recomputed in K6.
__global__ __launch_bounds__(256) void k_scatter(const void* __restrict__ ei,
                                                 const int* __restrict__ flag,
                                                 const int* __restrict__ rowptr,
                                                 const unsigned short* __restrict__ rank,
                                                 unsigned* __restrict__ srcs, int E) {
    int e = blockIdx.x * blockDim.x + threadIdx.x;
    if (e >= E) return;
    int is64 = *flag;
    int s, d;
    load_edge(ei, E, is64, e, s, d);
    int pos = rowptr[d] + (int)rank[e];
    __builtin_nontemporal_store((unsigned)s, srcs + pos);
}

// K6: fused per-node aggregation + elu + linear + log_softmax. One wave per
// node, 4 waves/block; 4 edge-slots x 16 lanes; lane c owns bytes 8c..8c+7 of
// the 128B-padded row (one dwordx2, branch-free). ev recomputed per edge from
// a_src[sj] (L2-resident 400KB gather) + uniform a_dst[n]. Hand-pipelined 2
// edges per lane-slot per iteration. Epilogue matvec spread over all 64 lanes.
__global__ __launch_bounds__(256) void k_gat_node(const int* __restrict__ rowptr,
                                                  const unsigned* __restrict__ srcs,
                                                  const float* __restrict__ a_src,
                                                  const float* __restrict__ a_dst,
                                                  const __half* __restrict__ h2,
                                                  const float* __restrict__ gat_bias,
                                                  const float* __restrict__ lin_W,
                                                  const float* __restrict__ lin_b,
                                                  float* __restrict__ out, int N) {
    __shared__ float Wl[HID * 17];   // stride-17 pad: conflict-free epilogue
    __shared__ float lb[OUT_CH];
    __shared__ float gb[HID];
    __shared__ float o_sm[4][HID];
    const int t = threadIdx.x;
    for (int i = t; i < HID * OUT_CH; i += 256) Wl[(i >> 4) * 17 + (i & 15)] = lin_W[i];
    if (t < OUT_CH) lb[t] = lin_b[t];
    if (t >= 64 && t < 64 + HID) gb[t - 64] = gat_bias[t - 64];
    __syncthreads();

    const int wv = t >> 6;
    const int lane = t & 63;
    const int slot = lane >> 4;   // 0..3
    const int c = lane & 15;      // 0..15 (c<12 carry real channels 4c..4c+3)
    const int n = blockIdx.x * 4 + wv;
    const bool active = n < N;

    if (active) {
        const int base = rowptr[n];
        const int deg = rowptr[n + 1] - base;
        const float adn = a_dst[n];
        const float ev_self = __expf(fminf(leaky(a_src[n] + adn), 50.f));
        const char* hb = (const char*)h2;

        float a0 = 0.f, a1 = 0.f, a2 = 0.f, a3 = 0.f, evsum = 0.f;
        if (slot == 0) {
            evsum = ev_self;
            uint2 hv = *(const uint2*)(hb + (size_t)n * ROWB + 8 * c);
            float2 f0 = __half22float2(*(const __half2*)&hv.x);
            float2 f1 = __half22float2(*(const __half2*)&hv.y);
            a0 = ev_self * f0.x; a1 = ev_self * f0.y;
            a2 = ev_self * f1.x; a3 = ev_self * f1.y;
        }
        int j = slot;
#pragma unroll 2
        for (; j + 4 < deg; j += 8) {
            unsigned s0 = srcs[base + j];
            unsigned s1 = srcs[base + j + 4];
            float as0 = a_src[s0];
            float as1 = a_src[s1];
            uint2 hv0 = *(const uint2*)(hb + (size_t)s0 * ROWB + 8 * c);
            uint2 hv1 = *(const uint2*)(hb + (size_t)s1 * ROWB + 8 * c);
            float ev0 = __expf(fminf(leaky(as0 + adn), 50.f));
            float ev1 = __expf(fminf(leaky(as1 + adn), 50.f));
            float2 f00 = __half22float2(*(const __half2*)&hv0.x);
            float2 f01 = __half22float2(*(const __half2*)&hv0.y);
            float2 f10 = __half22float2(*(const __half2*)&hv1.x);
            float2 f11 = __half22float2(*(const __half2*)&hv1.y);
            evsum += ev0; evsum += ev1;
            a0 += ev0 * f00.x; a1 += ev0 * f00.y;
            a2 += ev0 * f01.x; a3 += ev0 * f01.y;
            a0 += ev1 * f10.x; a1 += ev1 * f10.y;
            a2 += ev1 * f11.x; a3 += ev1 * f11.y;
        }
        if (j < deg) {
            unsigned s0 = srcs[base + j];
            float as0 = a_src[s0];
            uint2 hv = *(const uint2*)(hb + (size_t)s0 * ROWB + 8 * c);
            float ev = __expf(fminf(leaky(as0 + adn), 50.f));
            float2 f0 = __half22float2(*(const __half2*)&hv.x);
            float2 f1 = __half22float2(*(const __half2*)&hv.y);
            evsum += ev;
            a0 += ev * f0.x; a1 += ev * f0.y;
            a2 += ev * f1.x; a3 += ev * f1.y;
        }
        // cross-slot reduction (per-c values distinct per slot)
        evsum += __shfl_xor(evsum, 16); evsum += __shfl_xor(evsum, 32);
        a0 += __shfl_xor(a0, 16); a0 += __shfl_xor(a0, 32);
        a1 += __shfl_xor(a1, 16); a1 += __shfl_xor(a1, 32);
        a2 += __shfl_xor(a2, 16); a2 += __shfl_xor(a2, 32);
        a3 += __shfl_xor(a3, 16); a3 += __shfl_xor(a3, 32);
        const float inv = 1.f / evsum;
        if (slot == 0 && c < 12) {
            float4 v = make_float4(elu(a0 * inv + gb[4 * c + 0]),
                                   elu(a1 * inv + gb[4 * c + 1]),
                                   elu(a2 * inv + gb[4 * c + 2]),
                                   elu(a3 * inv + gb[4 * c + 3]));
            *(float4*)&o_sm[wv][4 * c] = v;
        }
    }
    __syncthreads();

    if (active) {
        // epilogue on all 64 lanes: lane (q=slot, oc=c) sums k in [12q,12q+12)
        const float* o = o_sm[wv];
        float z = 0.f;
#pragma unroll
        for (int i = 0; i < 12; ++i) {
            int k = 12 * slot + i;
            z += o[k] * Wl[k * 17 + c];
        }
        z += __shfl_xor(z, 16); z += __shfl_xor(z, 32);
        z += lb[c];
        float mx = z;
#pragma unroll
        for (int off = 8; off; off >>= 1) mx = fmaxf(mx, __shfl_xor(mx, off, 16));
        float ev = __expf(z - mx);
#pragma unroll
        for (int off = 8; off; off >>= 1) ev += __shfl_xor(ev, off, 16);
        float lse = mx + __logf(ev);
        if (slot == 0) out[(size_t)n * OUT_CH + c] = z - lse;
    }
}

extern "C" void kernel_launch(void* const* d_in, const int* in_sizes, int n_in,
                              void* d_out, int out_size, void* d_ws, size_t ws_size,
                              hipStream_t stream) {
    const float* x = (const float*)d_in[0];
    const void* edge_index = d_in[1];
    const float* W = (const float*)d_in[2];
    const float* att_src = (const float*)d_in[3];
    const float* att_dst = (const float*)d_in[4];
    const float* gat_bias = (const float*)d_in[5];
    const float* lin_W = (const float*)d_in[6];
    const float* lin_b = (const float*)d_in[7];
    float* out = (float*)d_out;

    const int N = in_sizes[0] / IN_CH;
    const int E = in_sizes[1] / 2;

    __half* h2 = (__half*)d_ws;                    // N rows x 128B (12.8MB)
    float* a_src = (float*)((char*)d_ws + (size_t)N * ROWB);  // N
    float* a_dst = a_src + N;                      // N
    int* rowptr = (int*)(a_dst + N);               // N+1
    int* degbuf = rowptr + N + 1;                  // N
    int* bsum = degbuf + N;                        // 64
    int* flag = bsum + 64;                         // 1
    unsigned short* rank = (unsigned short*)(flag + 1);       // E (2B, E even)
    unsigned* srcs =
        (unsigned*)(((uintptr_t)(rank + E) + 3) & ~(uintptr_t)3);  // E x 4B

    const int nodeBlocks = (N + 255) / 256;
    const int edgeBlocks = (E + 255) / 256;
    const int scanBlocks = (N + SCAN_ELEMS - 1) / SCAN_ELEMS;

    k_detect<<<1, 64, 0, stream>>>((const unsigned*)edge_index, flag);
    k_xw<<<(N + BLK_NODES - 1) / BLK_NODES, 256, 0, stream>>>(x, W, att_src, att_dst,
                                                              h2, a_src, a_dst, degbuf, N);
    k_count<<<edgeBlocks, 256, 0, stream>>>(edge_index, flag, degbuf, rank, E);
    k_scan_block<<<scanBlocks, 256, 0, stream>>>(degbuf, rowptr, bsum, N);
    k_scan_add<<<nodeBlocks, 256, 0, stream>>>(rowptr, bsum, N, E);
    k_scatter<<<edgeBlocks, 256, 0, stream>>>(edge_index, flag, rowptr, rank, srcs, E);
    k_gat_node<<<(N + 3) / 4, 256, 0, stream>>>(rowptr, srcs, a_src, a_dst,
                                                h2, gat_bias, lin_W, lin_b, out, N);
}

// Round 11
// 233.594 us; speedup vs baseline: 1.1828x; 1.0111x over previous
//
#include <hip/hip_runtime.h>
#include <hip/hip_fp16.h>

#define IN_CH 128
#define HID 48
#define OUT_CH 16
#define NEG_SLOPE 0.2f
#define SCAN_ELEMS 2048   // per block: 256 threads x 8
#define ROWB 128          // padded h2 row stride in bytes (48 halves + 16 pad)

__device__ __forceinline__ float leaky(float x) { return x >= 0.f ? x : NEG_SLOPE * x; }
__device__ __forceinline__ float elu(float x) { return x > 0.f ? x : __expf(x) - 1.f; }

// Edge index fetch that tolerates either int32 or int64 storage.
__device__ __forceinline__ void load_edge(const void* ei, int E, int is64, int e,
                                          int& s, int& d) {
    if (is64) {
        const long long* p = (const long long*)ei;
        s = (int)p[e];
        d = (int)p[(size_t)E + e];
    } else {
        const int* p = (const int*)ei;
        s = p[e];
        d = p[(size_t)E + e];
    }
}

// K1: h = x @ W (stored fp16, 128B-padded rows) fused with a_src/a_dst, deg
// zeroing, and the int64/int32 edge_index probe (block 0).
#define BLK_NODES 256
__global__ __launch_bounds__(256, 2) void k_xw(const float* __restrict__ x,
                                               const float* __restrict__ W,
                                               const float* __restrict__ att_src,
                                               const float* __restrict__ att_dst,
                                               const unsigned* __restrict__ ei,
                                               __half* __restrict__ h2,
                                               float* __restrict__ a_src,
                                               float* __restrict__ a_dst,
                                               int* __restrict__ deg,
                                               int* __restrict__ flag, int N) {
    __shared__ float Wl[IN_CH * HID];
    __shared__ float xl[BLK_NODES * 33];
    const int t = threadIdx.x;
    if (blockIdx.x == 0 && t == 0) {
        unsigned sdet = 0;
        for (int i = 1; i < 128; i += 2) sdet |= ei[i];
        *flag = (sdet == 0) ? 1 : 0;
    }
    for (int i = t; i < IN_CH * HID / 4; i += 256)
        ((float4*)Wl)[i] = ((const float4*)W)[i];
    const int n0 = blockIdx.x * BLK_NODES;
    const int kq = t & 3;
    const int ng = t >> 2;
    const int k0 = kq * 12;

    float acc[4][12];
#pragma unroll
    for (int i = 0; i < 4; ++i)
#pragma unroll
        for (int j = 0; j < 12; ++j) acc[i][j] = 0.f;

    for (int c0 = 0; c0 < IN_CH; c0 += 32) {
        __syncthreads();
#pragma unroll
        for (int p = 0; p < 8; ++p) {
            int id = t + p * 256;
            int row = id >> 3;
            int seg = id & 7;
            int n = n0 + row;
            float4 v = make_float4(0.f, 0.f, 0.f, 0.f);
            if (n < N) v = ((const float4*)(x + (size_t)n * IN_CH + c0))[seg];
            float* dst = &xl[row * 33 + seg * 4];
            dst[0] = v.x; dst[1] = v.y; dst[2] = v.z; dst[3] = v.w;
        }
        __syncthreads();
#pragma unroll 8
        for (int cc = 0; cc < 32; ++cc) {
            int c = c0 + cc;
            float xv[4];
#pragma unroll
            for (int i = 0; i < 4; ++i) xv[i] = xl[(ng * 4 + i) * 33 + cc];
            const float* wr = &Wl[c * HID + k0];
#pragma unroll
            for (int j = 0; j < 12; ++j) {
                float wv = wr[j];
#pragma unroll
                for (int i = 0; i < 4; ++i) acc[i][j] += xv[i] * wv;
            }
        }
    }
#pragma unroll
    for (int i = 0; i < 4; ++i) {
        int n = n0 + ng * 4 + i;
        if (n < N) {
            uint* dst = (uint*)((char*)h2 + (size_t)n * ROWB) + k0 / 2;
#pragma unroll
            for (int j = 0; j < 6; ++j) {
                __half2 hv = __floats2half2_rn(acc[i][2 * j], acc[i][2 * j + 1]);
                dst[j] = *(const uint*)&hv;
            }
        }
    }
    // zero the 32B row padding (halves 48..63): 256 rows x 8 uints / 256 thr.
#pragma unroll
    for (int p = 0; p < 8; ++p) {
        int id = t + p * 256;
        int row = id >> 3;
        int seg = id & 7;
        int n = n0 + row;
        if (n < N) ((uint*)((char*)h2 + (size_t)n * ROWB))[24 + seg] = 0u;
    }
    // fused attention terms: partial dot over this thread's 12 channels,
    // reduce across the 4 kq lanes.
    float as_[4], ad_[4];
#pragma unroll
    for (int i = 0; i < 4; ++i) {
        float s1 = 0.f, s2 = 0.f;
#pragma unroll
        for (int j = 0; j < 12; ++j) {
            float a = acc[i][j];
            s1 += a * att_src[k0 + j];
            s2 += a * att_dst[k0 + j];
        }
        s1 += __shfl_xor(s1, 1); s1 += __shfl_xor(s1, 2);
        s2 += __shfl_xor(s2, 1); s2 += __shfl_xor(s2, 2);
        as_[i] = s1; ad_[i] = s2;
    }
    if (kq == 0) {
#pragma unroll
        for (int i = 0; i < 4; ++i) {
            int n = n0 + ng * 4 + i;
            if (n < N) { a_src[n] = as_[i]; a_dst[n] = ad_[i]; }
        }
    }
    {
        int n = n0 + t;
        if (n < N) deg[n] = 0;
    }
}

// K3: in-degree count (destination half only); atomic return = rank (ushort).
__global__ __launch_bounds__(256) void k_count(const void* __restrict__ ei,
                                               const int* __restrict__ flag,
                                               int* __restrict__ deg,
                                               unsigned short* __restrict__ rank, int E) {
    int e = blockIdx.x * blockDim.x + threadIdx.x;
    if (e >= E) return;
    int d = (*flag) ? (int)((const long long*)ei)[(size_t)E + e]
                    : ((const int*)ei)[(size_t)E + e];
    rank[e] = (unsigned short)atomicAdd(&deg[d], 1);
}

// K4a: per-block exclusive scan of deg -> rowptr (local), block sums -> bsum
__global__ __launch_bounds__(256) void k_scan_block(const int* __restrict__ deg,
                                                    int* __restrict__ rowptr,
                                                    int* __restrict__ bsum, int N) {
    __shared__ int sm[256];
    const int t = threadIdx.x;
    const int base = blockIdx.x * SCAN_ELEMS + t * 8;
    int v[8];
    int s = 0;
#pragma unroll
    for (int i = 0; i < 8; ++i) {
        v[i] = (base + i < N) ? deg[base + i] : 0;
        s += v[i];
    }
    sm[t] = s;
    __syncthreads();
    for (int off = 1; off < 256; off <<= 1) {
        int y = (t >= off) ? sm[t - off] : 0;
        __syncthreads();
        sm[t] += y;
        __syncthreads();
    }
    int run = sm[t] - s;
#pragma unroll
    for (int i = 0; i < 8; ++i) {
        if (base + i < N) rowptr[base + i] = run;
        run += v[i];
    }
    if (t == 255) bsum[blockIdx.x] = sm[255];
}

// K4b: add block offsets (thread 0 sums the <=48 preceding chunk totals);
// set rowptr[N]=E.
__global__ __launch_bounds__(256) void k_scan_add(int* __restrict__ rowptr,
                                                  const int* __restrict__ bsum, int N, int E) {
    __shared__ int soff;
    const int chunk = (int)(((long long)blockIdx.x * 256) / SCAN_ELEMS);
    if (threadIdx.x == 0) {
        int run = 0;
        for (int b = 0; b < chunk; ++b) run += bsum[b];
        soff = run;
    }
    __syncthreads();
    int i = blockIdx.x * 256 + threadIdx.x;
    if (i == 0) rowptr[N] = E;
    if (i >= N) return;
    rowptr[i] += soff;
}

// K5: scatter edges into CSR (no atomics): pos = rowptr[d] + rank[e].
// ONE 4B nontemporal store per edge (src only); ev recomputed in K6.
__global__ __launch_bounds__(256) void k_scatter(const void* __restrict__ ei,
                                                 const int* __restrict__ flag,
                                                 const int* __restrict__ rowptr,
                                                 const unsigned short* __restrict__ rank,
                                                 unsigned* __restrict__ srcs, int E) {
    int e = blockIdx.x * blockDim.x + threadIdx.x;
    if (e >= E) return;
    int is64 = *flag;
    int s, d;
    load_edge(ei, E, is64, e, s, d);
    int pos = rowptr[d] + (int)rank[e];
    __builtin_nontemporal_store((unsigned)s, srcs + pos);
}

// K6: fused per-node aggregation + elu + linear + log_softmax. One wave per
// node, 4 waves/block. Per 64-edge chunk: each lane STAGES one edge (coalesced
// srcs load, one a_src gather, one exp) into LDS as packed (ev,src) — the exp
// and a_src work is done ONCE per edge instead of 16x. The 4-slot x 16-lane
// aggregation loop then reads (ev,src) from LDS (broadcast, free) and does one
// uint2 gather + 4 mixed fp16*fp32 FMAs. evsum is accumulated lane-privately
// during staging and reduced once at the end.
__global__ __launch_bounds__(256) void k_gat_node(const int* __restrict__ rowptr,
                                                  const unsigned* __restrict__ srcs,
                                                  const float* __restrict__ a_src,
                                                  const float* __restrict__ a_dst,
                                                  const __half* __restrict__ h2,
                                                  const float* __restrict__ gat_bias,
                                                  const float* __restrict__ lin_W,
                                                  const float* __restrict__ lin_b,
                                                  float* __restrict__ out, int N) {
    __shared__ float Wl[HID * 17];   // stride-17 pad for epilogue
    __shared__ float lb[OUT_CH];
    __shared__ float gb[HID];
    __shared__ float o_sm[4][HID];
    __shared__ unsigned long long evb[4][64];
    const int t = threadIdx.x;
    for (int i = t; i < HID * OUT_CH; i += 256) Wl[(i >> 4) * 17 + (i & 15)] = lin_W[i];
    if (t < OUT_CH) lb[t] = lin_b[t];
    if (t >= 64 && t < 64 + HID) gb[t - 64] = gat_bias[t - 64];
    __syncthreads();

    const int wv = t >> 6;
    const int lane = t & 63;
    const int slot = lane >> 4;   // 0..3
    const int c = lane & 15;      // 0..15 (c<12 carry real channels 4c..4c+3)
    const int n = blockIdx.x * 4 + wv;
    const bool active = n < N;

    if (active) {
        const int base = rowptr[n];
        const int deg = rowptr[n + 1] - base;
        const float adn = a_dst[n];
        const float ev_self = __expf(fminf(leaky(a_src[n] + adn), 50.f));
        const char* hb = (const char*)h2;

        float a0 = 0.f, a1 = 0.f, a2 = 0.f, a3 = 0.f;
        float evsum = (lane == 0) ? ev_self : 0.f;
        if (slot == 0) {
            uint2 hv = *(const uint2*)(hb + (size_t)n * ROWB + 8 * c);
            __half2 h01 = *(const __half2*)&hv.x;
            __half2 h23 = *(const __half2*)&hv.y;
            a0 = ev_self * __low2float(h01);
            a1 = ev_self * __high2float(h01);
            a2 = ev_self * __low2float(h23);
            a3 = ev_self * __high2float(h23);
        }
        for (int c0 = 0; c0 < deg; c0 += 64) {
            // stage: one edge per lane
            int j = c0 + lane;
            unsigned s = 0;
            float ev = 0.f;
            if (j < deg) {
                s = srcs[base + j];
                ev = __expf(fminf(leaky(a_src[s] + adn), 50.f));
            }
            evsum += ev;
            evb[wv][lane] = ((unsigned long long)__float_as_uint(ev) << 32) | s;
            // aggregate this chunk: 4 slots x 16 channel-lanes
            const int cnt = (deg - c0 < 64) ? (deg - c0) : 64;
#pragma unroll 4
            for (int jj = slot; jj < cnt; jj += 4) {
                unsigned long long pr = evb[wv][jj];
                unsigned sj = (unsigned)pr;
                float evj = __uint_as_float((unsigned)(pr >> 32));
                uint2 hv = *(const uint2*)(hb + (size_t)sj * ROWB + 8 * c);
                __half2 h01 = *(const __half2*)&hv.x;
                __half2 h23 = *(const __half2*)&hv.y;
                a0 += evj * __low2float(h01);
                a1 += evj * __high2float(h01);
                a2 += evj * __low2float(h23);
                a3 += evj * __high2float(h23);
            }
        }
        // evsum: full 64-lane reduce (each lane holds distinct staged partial)
#pragma unroll
        for (int off = 1; off < 64; off <<= 1) evsum += __shfl_xor(evsum, off);
        // acc: cross-slot reduction (per-c values distinct per slot)
        a0 += __shfl_xor(a0, 16); a0 += __shfl_xor(a0, 32);
        a1 += __shfl_xor(a1, 16); a1 += __shfl_xor(a1, 32);
        a2 += __shfl_xor(a2, 16); a2 += __shfl_xor(a2, 32);
        a3 += __shfl_xor(a3, 16); a3 += __shfl_xor(a3, 32);
        const float inv = 1.f / evsum;
        if (slot == 0 && c < 12) {
            float4 v = make_float4(elu(a0 * inv + gb[4 * c + 0]),
                                   elu(a1 * inv + gb[4 * c + 1]),
                                   elu(a2 * inv + gb[4 * c + 2]),
                                   elu(a3 * inv + gb[4 * c + 3]));
            *(float4*)&o_sm[wv][4 * c] = v;
        }
    }
    __syncthreads();

    if (active) {
        // epilogue on all 64 lanes: lane (q=slot, oc=c) sums k in [12q,12q+12)
        const float* o = o_sm[wv];
        float z = 0.f;
#pragma unroll
        for (int i = 0; i < 12; ++i) {
            int k = 12 * slot + i;
            z += o[k] * Wl[k * 17 + c];
        }
        z += __shfl_xor(z, 16); z += __shfl_xor(z, 32);
        z += lb[c];
        float mx = z;
#pragma unroll
        for (int off = 8; off; off >>= 1) mx = fmaxf(mx, __shfl_xor(mx, off, 16));
        float ev = __expf(z - mx);
#pragma unroll
        for (int off = 8; off; off >>= 1) ev += __shfl_xor(ev, off, 16);
        float lse = mx + __logf(ev);
        if (slot == 0) out[(size_t)n * OUT_CH + c] = z - lse;
    }
}

extern "C" void kernel_launch(void* const* d_in, const int* in_sizes, int n_in,
                              void* d_out, int out_size, void* d_ws, size_t ws_size,
                              hipStream_t stream) {
    const float* x = (const float*)d_in[0];
    const void* edge_index = d_in[1];
    const float* W = (const float*)d_in[2];
    const float* att_src = (const float*)d_in[3];
    const float* att_dst = (const float*)d_in[4];
    const float* gat_bias = (const float*)d_in[5];
    const float* lin_W = (const float*)d_in[6];
    const float* lin_b = (const float*)d_in[7];
    float* out = (float*)d_out;

    const int N = in_sizes[0] / IN_CH;
    const int E = in_sizes[1] / 2;

    __half* h2 = (__half*)d_ws;                    // N rows x 128B (12.8MB)
    float* a_src = (float*)((char*)d_ws + (size_t)N * ROWB);  // N
    float* a_dst = a_src + N;                      // N
    int* rowptr = (int*)(a_dst + N);               // N+1
    int* degbuf = rowptr + N + 1;                  // N
    int* bsum = degbuf + N;                        // 64
    int* flag = bsum + 64;                         // 1
    unsigned short* rank = (unsigned short*)(flag + 1);       // E (2B, E even)
    unsigned* srcs =
        (unsigned*)(((uintptr_t)(rank + E) + 3) & ~(uintptr_t)3);  // E x 4B

    const int nodeBlocks = (N + 255) / 256;
    const int edgeBlocks = (E + 255) / 256;
    const int scanBlocks = (N + SCAN_ELEMS - 1) / SCAN_ELEMS;

    k_xw<<<(N + BLK_NODES - 1) / BLK_NODES, 256, 0, stream>>>(
        x, W, att_src, att_dst, (const unsigned*)edge_index,
        h2, a_src, a_dst, degbuf, flag, N);
    k_count<<<edgeBlocks, 256, 0, stream>>>(edge_index, flag, degbuf, rank, E);
    k_scan_block<<<scanBlocks, 256, 0, stream>>>(degbuf, rowptr, bsum, N);
    k_scan_add<<<nodeBlocks, 256, 0, stream>>>(rowptr, bsum, N, E);
    k_scatter<<<edgeBlocks, 256, 0, stream>>>(edge_index, flag, rowptr, rank, srcs, E);
    k_gat_node<<<(N + 3) / 4, 256, 0, stream>>>(rowptr, srcs, a_src, a_dst,
                                                h2, gat_bias, lin_W, lin_b, out, N);
}